// Round 10
// baseline (58.294 us; speedup 1.0000x reference)
//
#include <hip/hip_runtime.h>
#include <hip/hip_bf16.h>
#include <math.h>

#define NPOS 8192
#define CIN 64
#define CQK 8
#define NB 2
#define LOG2E 1.4426950408889634f
#define SOFF 16.0f   // fixed log2-domain softmax offset
#define KSPL 4       // key splits per batch
#define KH (NPOS / KSPL)     // 2048 keys per flash block
#define STEPS (KH / 64)      // 32 staged 64-key steps

typedef __attribute__((ext_vector_type(8))) short bf16x8;
typedef __attribute__((ext_vector_type(16))) float f32x16;

typedef __attribute__((address_space(3))) void lds_void;
typedef __attribute__((address_space(1))) const void glb_void;

__device__ __forceinline__ unsigned short f2bf(float f) {
  union { float f; unsigned int u; } a; a.f = f;
  unsigned int r = a.u + 0x7FFFu + ((a.u >> 16) & 1u);
  return (unsigned short)(r >> 16);
}

// ---------------- QKV projection ---------------- (unchanged structure)
__global__ __launch_bounds__(256, 2) void qkv_proj(
    const float* __restrict__ x,
    const float* __restrict__ Wq, const float* __restrict__ bq,
    const float* __restrict__ Wk, const float* __restrict__ bk,
    const float* __restrict__ Wv, const float* __restrict__ bv,
    unsigned short* __restrict__ Qb, unsigned short* __restrict__ Kb,
    unsigned short* __restrict__ VB) {
  __shared__ float sWq[CQK * CIN], sWk[CQK * CIN], sWv[CIN * CIN], sb[2 * CQK + CIN];
  __shared__ unsigned short sV[32][66];
  int t = threadIdx.x;
  for (int i = t; i < CQK * CIN; i += 256) { sWq[i] = Wq[i] * LOG2E; sWk[i] = Wk[i]; }
  for (int i = t; i < CIN * CIN; i += 256) sWv[i] = Wv[i];
  if (t < CQK) sb[t] = bq[t] * LOG2E;
  if (t >= CQK && t < 2 * CQK) sb[t] = bk[t - CQK];
  if (t >= 2 * CQK && t < 2 * CQK + CIN) sb[t] = bv[t - 2 * CQK];
  __syncthreads();

  int p_loc = t & 31, grp = t >> 5;
  int gid = blockIdx.x * 32 + p_loc;
  int b = gid >> 13;
  int n = gid & (NPOS - 1);
  const float* xp = x + (size_t)b * CIN * NPOS + n;
  float xv[CIN];
#pragma unroll
  for (int c = 0; c < CIN; ++c) xv[c] = xp[(size_t)c * NPOS];

  {
    int o = grp;
    float aq = sb[o], ak = sb[CQK + o];
    const float4* wq4 = (const float4*)&sWq[o * CIN];
    const float4* wk4 = (const float4*)&sWk[o * CIN];
#pragma unroll
    for (int c4 = 0; c4 < 16; ++c4) {
      float4 wq = wq4[c4], wk = wk4[c4];
      float x0 = xv[4 * c4], x1 = xv[4 * c4 + 1], x2 = xv[4 * c4 + 2], x3 = xv[4 * c4 + 3];
      aq += wq.x * x0 + wq.y * x1 + wq.z * x2 + wq.w * x3;
      ak += wk.x * x0 + wk.y * x1 + wk.z * x2 + wk.w * x3;
    }
    Qb[(size_t)gid * CQK + o] = f2bf(aq);
    Kb[(size_t)gid * CQK + o] = f2bf(ak);
  }
#pragma unroll
  for (int oo = 0; oo < 8; ++oo) {
    int o = grp * 8 + oo;
    float av = sb[2 * CQK + o];
    const float4* wv4 = (const float4*)&sWv[o * CIN];
#pragma unroll
    for (int c4 = 0; c4 < 16; ++c4) {
      float4 w = wv4[c4];
      av += w.x * xv[4 * c4] + w.y * xv[4 * c4 + 1] + w.z * xv[4 * c4 + 2] + w.w * xv[4 * c4 + 3];
    }
    sV[p_loc][o] = f2bf(av);
  }
  __syncthreads();

  {
    int gid0 = blockIdx.x * 32;
    int bb = gid0 >> 13;
    int jb = (gid0 & (NPOS - 1)) >> 5;
    int f = t >> 6;
    int ln = t & 63;
    int ch = ((f >> 1) << 5) + (ln & 31);
    int w0 = ((f & 1) << 4) + (((ln >> 5) & 1) << 2);
    union { unsigned short s[8]; bf16x8 v; } ou;
#pragma unroll
    for (int i = 0; i < 8; ++i) {
      int p = w0 + (i & 3) + (((i >> 2) & 1) << 3);
      ou.s[i] = sV[p][ch];
    }
    *reinterpret_cast<bf16x8*>(
        VB + (((size_t)bb * 256 + jb) * 2048 + (size_t)f * 512 + ln * 8)) = ou.v;
  }
}

// ---------------- Flash attention, LDS-shared V ----------------
// 256 blocks = 64 q-blocks (256 q) x 4 key-splits (2048 keys). 512 threads.
// Each wave owns 32 queries (independent acc, no cross-wave merge).
// Per 64-key step: all 8 waves cooperatively stage V(8KB)+K(1KB) into LDS via
// global_load_lds (double-buffered, 1 barrier/step), then every wave reads the
// SAME tile from LDS -> V fetched from L2 once per block instead of 8x.
__global__ __launch_bounds__(512, 2) void flash_attn(
    const unsigned short* __restrict__ Qb, const unsigned short* __restrict__ Kb,
    const unsigned short* __restrict__ VB,
    float* __restrict__ Opart, float* __restrict__ lpart) {
  __shared__ unsigned short sbuf[2][4608];  // per buf: V 4096 shorts + K 512 shorts
  __shared__ float sep[8][64][33];          // per-wave epilogue transpose

  int tid = threadIdx.x;
  int wave = tid >> 6, lane = tid & 63;
  int qcol = lane & 31, hi = lane >> 5;
  int blk = blockIdx.x;
  int qb = blk >> 2, ks = blk & 3;
  int b = qb >> 5;
  int kbase = ks * KH;                       // key offset within batch
  int jbBase = (ks * KH) >> 5;               // 32-key tile index base

  // Q fragment: wave owns queries qb*256 + wave*32 + (0..31)
  bf16x8 qfrag;
#pragma unroll
  for (int i = 0; i < 8; ++i) qfrag[i] = 0;
  if (!hi) qfrag = *reinterpret_cast<const bf16x8*>(
      Qb + ((size_t)qb * 256 + wave * 32 + qcol) * CQK);

  f32x16 z;
#pragma unroll
  for (int i = 0; i < 16; ++i) z[i] = -SOFF;
  f32x16 acc0, acc1;   // O^T[c][q]: acc0 c=0..31, acc1 c=32..63
#pragma unroll
  for (int i = 0; i < 16; ++i) { acc0[i] = 0.f; acc1[i] = 0.f; }
  float l = 0.f;

  const unsigned short* Kp = Kb + (size_t)b * NPOS * CQK;
  const unsigned short* VBb = VB + (size_t)b * 256 * 2048;

  // stage(buf, step): V = 2 blocked tiles (8KB, contiguous), K = 64 keys (1KB)
  auto stage = [&](int buf, int step) {
    const unsigned short* vsrc =
        VBb + ((size_t)(jbBase + step * 2)) * 2048 + wave * 512 + lane * 8;
    __builtin_amdgcn_global_load_lds((glb_void*)vsrc,
                                     (lds_void*)&sbuf[buf][wave * 512], 16, 0, 0);
    if (wave == 0) {
      const unsigned short* ksrc = Kp + ((size_t)(kbase + step * 64)) * CQK + lane * 8;
      __builtin_amdgcn_global_load_lds((glb_void*)ksrc,
                                       (lds_void*)&sbuf[buf][4096], 16, 0, 0);
    }
  };

  stage(0, 0);
  __syncthreads();   // drains vmcnt: buf0 ready

  for (int step = 0; step < STEPS; ++step) {
    int cur = step & 1;
    if (step + 1 < STEPS) stage(cur ^ 1, step + 1);   // issue next-tile loads first

#pragma unroll
    for (int u = 0; u < 2; ++u) {
      // K fragment from LDS (broadcast across hi halves; hi garbage * Q-zeros)
      bf16x8 kfrag = *reinterpret_cast<const bf16x8*>(
          &sbuf[cur][4096 + u * 256 + qcol * 8]);
      f32x16 S = __builtin_amdgcn_mfma_f32_32x32x16_bf16(kfrag, qfrag, z, 0, 0, 0);

      // V fragments from LDS
      const unsigned short* vb = &sbuf[cur][u * 2048];
      bf16x8 va0 = *reinterpret_cast<const bf16x8*>(vb + (size_t)lane * 8);
      bf16x8 va1 = *reinterpret_cast<const bf16x8*>(vb + 512 + (size_t)lane * 8);
      bf16x8 vb0 = *reinterpret_cast<const bf16x8*>(vb + 1024 + (size_t)lane * 8);
      bf16x8 vb1 = *reinterpret_cast<const bf16x8*>(vb + 1536 + (size_t)lane * 8);

      // p = exp2(S); pack pairs to bf16 via v_perm (truncation)
      unsigned int pk[8];
      float ls0 = 0.f, ls1 = 0.f;
#pragma unroll
      for (int jj = 0; jj < 8; ++jj) {
        float pa = __builtin_amdgcn_exp2f(S[2 * jj]);
        float pb = __builtin_amdgcn_exp2f(S[2 * jj + 1]);
        ls0 += pa; ls1 += pb;
        pk[jj] = __builtin_amdgcn_perm(__float_as_uint(pb), __float_as_uint(pa),
                                       0x07060302u);
      }
      l += ls0 + ls1;

      union { unsigned int ui[4]; bf16x8 v; } PA0, PA1;
      PA0.ui[0] = pk[0]; PA0.ui[1] = pk[1]; PA0.ui[2] = pk[2]; PA0.ui[3] = pk[3];
      PA1.ui[0] = pk[4]; PA1.ui[1] = pk[5]; PA1.ui[2] = pk[6]; PA1.ui[3] = pk[7];

      acc0 = __builtin_amdgcn_mfma_f32_32x32x16_bf16(va0, PA0.v, acc0, 0, 0, 0);
      acc0 = __builtin_amdgcn_mfma_f32_32x32x16_bf16(va1, PA1.v, acc0, 0, 0, 0);
      acc1 = __builtin_amdgcn_mfma_f32_32x32x16_bf16(vb0, PA0.v, acc1, 0, 0, 0);
      acc1 = __builtin_amdgcn_mfma_f32_32x32x16_bf16(vb1, PA1.v, acc1, 0, 0, 0);
    }
    __syncthreads();  // everyone done reading buf[cur]; next stage drained
  }

  // -------- per-wave epilogue: l reduce + transposed partial-O store --------
  float l2 = l + __shfl_xor(l, 32);
  if (!hi) lpart[((qb << 2) + ks) * 256 + wave * 32 + qcol] = l2;

#pragma unroll
  for (int r = 0; r < 16; ++r) {
    int c0 = (r & 3) + ((r >> 2) << 3) + (hi << 2);
    sep[wave][c0][qcol] = acc0[r];
    sep[wave][c0 + 32][qcol] = acc1[r];
  }
  // coalesced write-out: Opart[qb][ks][c][256q]
  float* Ob = Opart + (((size_t)(qb << 2) + ks) << 6) * 256;
#pragma unroll
  for (int cc = 0; cc < 32; ++cc) {
    int c = (cc << 1) | hi;
    Ob[(size_t)c * 256 + wave * 32 + qcol] = sep[wave][c][qcol];
  }
}

// ---------------- Merge: sum 4 key-split partials, apply gamma/L + residual
__global__ __launch_bounds__(256) void pam_merge(
    const float* __restrict__ Opart, const float* __restrict__ lpart,
    const float* __restrict__ x, const float* __restrict__ gamma,
    float* __restrict__ out) {
  int blk = blockIdx.x;
  int qb = blk >> 3, oct = blk & 7;
  int t = threadIdx.x;
  int ql = oct * 32 + (t & 31);      // 0..255 within q-block
  int cg = t >> 5;                    // 0..7
  int gq = qb * 256 + ql;
  int b = gq >> 13, pos = gq & (NPOS - 1);

  float L = 0.f;
#pragma unroll
  for (int ksv = 0; ksv < KSPL; ++ksv) L += lpart[((qb << 2) + ksv) * 256 + ql];
  float gi = gamma[0] / L;

#pragma unroll
  for (int j = 0; j < 8; ++j) {
    int c = cg * 8 + j;
    float s = 0.f;
#pragma unroll
    for (int ksv = 0; ksv < KSPL; ++ksv)
      s += Opart[((((size_t)(qb << 2) + ksv) << 6) + c) * 256 + ql];
    size_t oidx = ((size_t)(b * CIN + c)) * NPOS + pos;
    out[oidx] = s * gi + x[oidx];
  }
}

extern "C" void kernel_launch(void* const* d_in, const int* in_sizes, int n_in,
                              void* d_out, int out_size, void* d_ws, size_t ws_size,
                              hipStream_t stream) {
  const float* x     = (const float*)d_in[0];
  const float* Wq    = (const float*)d_in[1];
  const float* bq    = (const float*)d_in[2];
  const float* Wk    = (const float*)d_in[3];
  const float* bk    = (const float*)d_in[4];
  const float* Wv    = (const float*)d_in[5];
  const float* bv    = (const float*)d_in[6];
  const float* gamma = (const float*)d_in[7];
  float* out = (float*)d_out;

  char* ws = (char*)d_ws;
  unsigned short* Qb = (unsigned short*)(ws);                    // 256 KB
  unsigned short* Kb = (unsigned short*)(ws + (256 << 10));      // 256 KB
  unsigned short* VB = (unsigned short*)(ws + (512 << 10));      // 2 MB blocked
  float* Opart = (float*)(ws + (4 << 20));                       // 16 MB
  float* lpart = (float*)(ws + (20 << 20));                      // 256 KB

  qkv_proj<<<dim3(NB * NPOS / 32), dim3(256), 0, stream>>>(
      x, Wq, bq, Wk, bk, Wv, bv, Qb, Kb, VB);
  flash_attn<<<dim3(64 * KSPL), dim3(512), 0, stream>>>(Qb, Kb, VB, Opart, lpart);
  pam_merge<<<dim3(64 * 8), dim3(256), 0, stream>>>(Opart, lpart, x, gamma, out);
}

// Round 11
// 45.717 us; speedup vs baseline: 1.2751x; 1.2751x over previous
//
#include <hip/hip_runtime.h>
#include <hip/hip_bf16.h>
#include <math.h>

#define NPOS 8192
#define CIN 64
#define CQK 8
#define NB 2
#define LOG2E 1.4426950408889634f
#define SOFF 16.0f   // fixed log2-domain softmax offset (replaces online max)

typedef __attribute__((ext_vector_type(8))) short bf16x8;
typedef __attribute__((ext_vector_type(16))) float f32x16;

__device__ __forceinline__ unsigned short f2bf(float f) {
  union { float f; unsigned int u; } a; a.f = f;
  unsigned int r = a.u + 0x7FFFu + ((a.u >> 16) & 1u);
  return (unsigned short)(r >> 16);
}

// ---------------- QKV projection ---------------- (unchanged from R8)
__global__ __launch_bounds__(256, 2) void qkv_proj(
    const float* __restrict__ x,
    const float* __restrict__ Wq, const float* __restrict__ bq,
    const float* __restrict__ Wk, const float* __restrict__ bk,
    const float* __restrict__ Wv, const float* __restrict__ bv,
    unsigned short* __restrict__ Qb, unsigned short* __restrict__ Kb,
    unsigned short* __restrict__ VB) {
  __shared__ float sWq[CQK * CIN], sWk[CQK * CIN], sWv[CIN * CIN], sb[2 * CQK + CIN];
  __shared__ unsigned short sV[32][66];
  int t = threadIdx.x;
  for (int i = t; i < CQK * CIN; i += 256) { sWq[i] = Wq[i] * LOG2E; sWk[i] = Wk[i]; }
  for (int i = t; i < CIN * CIN; i += 256) sWv[i] = Wv[i];
  if (t < CQK) sb[t] = bq[t] * LOG2E;
  if (t >= CQK && t < 2 * CQK) sb[t] = bk[t - CQK];
  if (t >= 2 * CQK && t < 2 * CQK + CIN) sb[t] = bv[t - 2 * CQK];
  __syncthreads();

  int p_loc = t & 31, grp = t >> 5;
  int gid = blockIdx.x * 32 + p_loc;
  int b = gid >> 13;
  int n = gid & (NPOS - 1);
  const float* xp = x + (size_t)b * CIN * NPOS + n;
  float xv[CIN];
#pragma unroll
  for (int c = 0; c < CIN; ++c) xv[c] = xp[(size_t)c * NPOS];

  {
    int o = grp;
    float aq = sb[o], ak = sb[CQK + o];
    const float4* wq4 = (const float4*)&sWq[o * CIN];
    const float4* wk4 = (const float4*)&sWk[o * CIN];
#pragma unroll
    for (int c4 = 0; c4 < 16; ++c4) {
      float4 wq = wq4[c4], wk = wk4[c4];
      float x0 = xv[4 * c4], x1 = xv[4 * c4 + 1], x2 = xv[4 * c4 + 2], x3 = xv[4 * c4 + 3];
      aq += wq.x * x0 + wq.y * x1 + wq.z * x2 + wq.w * x3;
      ak += wk.x * x0 + wk.y * x1 + wk.z * x2 + wk.w * x3;
    }
    Qb[(size_t)gid * CQK + o] = f2bf(aq);
    Kb[(size_t)gid * CQK + o] = f2bf(ak);
  }
#pragma unroll
  for (int oo = 0; oo < 8; ++oo) {
    int o = grp * 8 + oo;
    float av = sb[2 * CQK + o];
    const float4* wv4 = (const float4*)&sWv[o * CIN];
#pragma unroll
    for (int c4 = 0; c4 < 16; ++c4) {
      float4 w = wv4[c4];
      av += w.x * xv[4 * c4] + w.y * xv[4 * c4 + 1] + w.z * xv[4 * c4 + 2] + w.w * xv[4 * c4 + 3];
    }
    sV[p_loc][o] = f2bf(av);
  }
  __syncthreads();

  {
    int gid0 = blockIdx.x * 32;
    int bb = gid0 >> 13;
    int jb = (gid0 & (NPOS - 1)) >> 5;
    int f = t >> 6;
    int ln = t & 63;
    int ch = ((f >> 1) << 5) + (ln & 31);
    int w0 = ((f & 1) << 4) + (((ln >> 5) & 1) << 2);
    union { unsigned short s[8]; bf16x8 v; } ou;
#pragma unroll
    for (int i = 0; i < 8; ++i) {
      int p = w0 + (i & 3) + (((i >> 2) & 1) << 3);
      ou.s[i] = sV[p][ch];
    }
    *reinterpret_cast<bf16x8*>(
        VB + (((size_t)bb * 256 + jb) * 2048 + (size_t)f * 512 + ln * 8)) = ou.v;
  }
}

// ---------------- Flash attention: block = 64 queries (2 MFMA q-groups),
// 8 waves x 1024 keys (32 tiles each). Fixed-offset log2 softmax.
// Serial-latency cuts: V register-prefetched 2 tiles deep (issued right after
// the S MFMAs, consumed a full iteration later); l computed by ones-MFMA
// (removes 36 serial VALU adds/iter); exp2 on the trans pipe.
__global__ __launch_bounds__(512, 2) void flash_attn(
    const unsigned short* __restrict__ Qb, const unsigned short* __restrict__ Kb,
    const unsigned short* __restrict__ VB, const float* __restrict__ x,
    const float* __restrict__ gamma, float* __restrict__ out) {
  int tid = threadIdx.x;
  int wave = tid >> 6, lane = tid & 63;
  int qcol = lane & 31, hi = lane >> 5;
  int blk = blockIdx.x;
  int b = blk >> 7, qt = blk & 127;
  int qbase = qt * 64;

  bf16x8 qfrag0, qfrag1;
#pragma unroll
  for (int i = 0; i < 8; ++i) { qfrag0[i] = 0; qfrag1[i] = 0; }
  if (!hi) {
    qfrag0 = *reinterpret_cast<const bf16x8*>(Qb + ((size_t)b * NPOS + qbase + qcol) * CQK);
    qfrag1 = *reinterpret_cast<const bf16x8*>(Qb + ((size_t)b * NPOS + qbase + 32 + qcol) * CQK);
  }

  bf16x8 ones;   // bf16 1.0 (A-operand of the l-sum MFMA)
#pragma unroll
  for (int i = 0; i < 8; ++i) ones[i] = (short)0x3F80;

  f32x16 z;
#pragma unroll
  for (int i = 0; i < 16; ++i) z[i] = -SOFF;
  f32x16 accA0, accB0, accA1, accB1;  // [c 0-31 | c 32-63] x [q-group 0 | 1]
  f32x16 accL0, accL1;                // l[q] (all rows identical)
#pragma unroll
  for (int i = 0; i < 16; ++i) {
    accA0[i] = 0.f; accB0[i] = 0.f; accA1[i] = 0.f; accB1[i] = 0.f;
    accL0[i] = 0.f; accL1[i] = 0.f;
  }

  const unsigned short* Kp = Kb + (size_t)b * NPOS * CQK;
  const bf16x8* Vt = reinterpret_cast<const bf16x8*>(VB + (size_t)b * 256 * 2048);

  int jb0 = wave << 5;   // this wave's first 32-key tile (32 tiles per wave)
  bf16x8 kcur = *reinterpret_cast<const bf16x8*>(Kp + ((size_t)(jb0 << 5) + qcol) * CQK);

  // V prefetch, 2 tiles deep
  const bf16x8* tp0 = Vt + (size_t)jb0 * 256;
  const bf16x8* tp1 = Vt + (size_t)(jb0 + 1) * 256;
  bf16x8 vc0 = tp0[lane],       vc1 = tp0[64 + lane];
  bf16x8 vc2 = tp0[128 + lane], vc3 = tp0[192 + lane];
  bf16x8 vn0 = tp1[lane],       vn1 = tp1[64 + lane];
  bf16x8 vn2 = tp1[128 + lane], vn3 = tp1[192 + lane];

#pragma unroll 2
  for (int tt = 0; tt < 32; ++tt) {
    // S[key][query] = log2e*energy - 16, both q-groups share kcur
    f32x16 S0 = __builtin_amdgcn_mfma_f32_32x32x16_bf16(kcur, qfrag0, z, 0, 0, 0);
    f32x16 S1 = __builtin_amdgcn_mfma_f32_32x32x16_bf16(kcur, qfrag1, z, 0, 0, 0);

    // issue V(tt+2) and K(tt+1) loads now; consumed next iteration / below
    const bf16x8* tile2 = Vt + (size_t)(jb0 + ((tt + 2) & 31)) * 256;
    bf16x8 w0 = tile2[lane],       w1 = tile2[64 + lane];
    bf16x8 w2 = tile2[128 + lane], w3 = tile2[192 + lane];
    bf16x8 knx = *reinterpret_cast<const bf16x8*>(
        Kp + ((size_t)((jb0 + ((tt + 1) & 31)) << 5) + qcol) * CQK);

    // p = exp2(S); pack pairs to bf16 via v_perm (truncation)
    unsigned int pk0[8], pk1[8];
#pragma unroll
    for (int jj = 0; jj < 8; ++jj) {
      float pa = __builtin_amdgcn_exp2f(S0[2 * jj]);
      float pb = __builtin_amdgcn_exp2f(S0[2 * jj + 1]);
      float pc = __builtin_amdgcn_exp2f(S1[2 * jj]);
      float pd = __builtin_amdgcn_exp2f(S1[2 * jj + 1]);
      pk0[jj] = __builtin_amdgcn_perm(__float_as_uint(pb), __float_as_uint(pa), 0x07060302u);
      pk1[jj] = __builtin_amdgcn_perm(__float_as_uint(pd), __float_as_uint(pc), 0x07060302u);
    }

    union { unsigned int ui[4]; bf16x8 v; } PA00, PA10, PA01, PA11;
    PA00.ui[0] = pk0[0]; PA00.ui[1] = pk0[1]; PA00.ui[2] = pk0[2]; PA00.ui[3] = pk0[3];
    PA10.ui[0] = pk0[4]; PA10.ui[1] = pk0[5]; PA10.ui[2] = pk0[6]; PA10.ui[3] = pk0[7];
    PA01.ui[0] = pk1[0]; PA01.ui[1] = pk1[1]; PA01.ui[2] = pk1[2]; PA01.ui[3] = pk1[3];
    PA11.ui[0] = pk1[4]; PA11.ui[1] = pk1[5]; PA11.ui[2] = pk1[6]; PA11.ui[3] = pk1[7];

    // l-sum MFMAs first (short independent chains), then PV on current V regs
    accL0 = __builtin_amdgcn_mfma_f32_32x32x16_bf16(ones, PA00.v, accL0, 0, 0, 0);
    accL0 = __builtin_amdgcn_mfma_f32_32x32x16_bf16(ones, PA10.v, accL0, 0, 0, 0);
    accL1 = __builtin_amdgcn_mfma_f32_32x32x16_bf16(ones, PA01.v, accL1, 0, 0, 0);
    accL1 = __builtin_amdgcn_mfma_f32_32x32x16_bf16(ones, PA11.v, accL1, 0, 0, 0);

    accA0 = __builtin_amdgcn_mfma_f32_32x32x16_bf16(vc0, PA00.v, accA0, 0, 0, 0);
    accA0 = __builtin_amdgcn_mfma_f32_32x32x16_bf16(vc1, PA10.v, accA0, 0, 0, 0);
    accB0 = __builtin_amdgcn_mfma_f32_32x32x16_bf16(vc2, PA00.v, accB0, 0, 0, 0);
    accB0 = __builtin_amdgcn_mfma_f32_32x32x16_bf16(vc3, PA10.v, accB0, 0, 0, 0);
    accA1 = __builtin_amdgcn_mfma_f32_32x32x16_bf16(vc0, PA01.v, accA1, 0, 0, 0);
    accA1 = __builtin_amdgcn_mfma_f32_32x32x16_bf16(vc1, PA11.v, accA1, 0, 0, 0);
    accB1 = __builtin_amdgcn_mfma_f32_32x32x16_bf16(vc2, PA01.v, accB1, 0, 0, 0);
    accB1 = __builtin_amdgcn_mfma_f32_32x32x16_bf16(vc3, PA11.v, accB1, 0, 0, 0);

    // rotate prefetch registers (renamed away by unroll-2)
    vc0 = vn0; vc1 = vn1; vc2 = vn2; vc3 = vn3;
    vn0 = w0;  vn1 = w1;  vn2 = w2;  vn3 = w3;
    kcur = knx;
  }

  // -------- block-level merge of 8 wave-partials (pure l-sum) --------
  __shared__ float sL[8][64];
  __shared__ float sLinv[64];
  __shared__ float sacc[64][68];   // [q][c], pad 68 floats: rows 16B-aligned
  if (!hi) { sL[wave][qcol] = accL0[0]; sL[wave][32 + qcol] = accL1[0]; }
  __syncthreads();
  if (tid < 64) {
    float L = 0.f;
#pragma unroll
    for (int w2 = 0; w2 < 8; ++w2) L += sL[w2][tid];
    sLinv[tid] = 1.0f / L;
  }

  // acc merge: wave 0 writes, waves 1-7 accumulate (float4 LDS RMW)
  for (int w2 = 0; w2 < 8; ++w2) {
    __syncthreads();
    if (wave == w2) {
#pragma unroll
      for (int k = 0; k < 4; ++k) {
        int c0 = (k << 3) + (hi << 2);
        float4 cA0 = make_float4(accA0[4 * k], accA0[4 * k + 1], accA0[4 * k + 2], accA0[4 * k + 3]);
        float4 cB0 = make_float4(accB0[4 * k], accB0[4 * k + 1], accB0[4 * k + 2], accB0[4 * k + 3]);
        float4 cA1 = make_float4(accA1[4 * k], accA1[4 * k + 1], accA1[4 * k + 2], accA1[4 * k + 3]);
        float4 cB1 = make_float4(accB1[4 * k], accB1[4 * k + 1], accB1[4 * k + 2], accB1[4 * k + 3]);
        float4* pA0 = (float4*)&sacc[qcol][c0];
        float4* pB0 = (float4*)&sacc[qcol][c0 + 32];
        float4* pA1 = (float4*)&sacc[32 + qcol][c0];
        float4* pB1 = (float4*)&sacc[32 + qcol][c0 + 32];
        if (w2 == 0) { *pA0 = cA0; *pB0 = cB0; *pA1 = cA1; *pB1 = cB1; }
        else {
          float4 a = *pA0, bb = *pB0, c = *pA1, d = *pB1;
          a.x += cA0.x; a.y += cA0.y; a.z += cA0.z; a.w += cA0.w;
          bb.x += cB0.x; bb.y += cB0.y; bb.z += cB0.z; bb.w += cB0.w;
          c.x += cA1.x; c.y += cA1.y; c.z += cA1.z; c.w += cA1.w;
          d.x += cB1.x; d.y += cB1.y; d.z += cB1.z; d.w += cB1.w;
          *pA0 = a; *pB0 = bb; *pA1 = c; *pB1 = d;
        }
      }
    }
  }
  __syncthreads();

  float g = gamma[0];
  for (int i = tid; i < CIN * 64; i += 512) {
    int c = i >> 6, q = i & 63;
    size_t idx = ((size_t)b * CIN + c) * NPOS + qbase + q;
    out[idx] = g * sacc[q][c] * sLinv[q] + x[idx];
  }
}

extern "C" void kernel_launch(void* const* d_in, const int* in_sizes, int n_in,
                              void* d_out, int out_size, void* d_ws, size_t ws_size,
                              hipStream_t stream) {
  const float* x     = (const float*)d_in[0];
  const float* Wq    = (const float*)d_in[1];
  const float* bq    = (const float*)d_in[2];
  const float* Wk    = (const float*)d_in[3];
  const float* bk    = (const float*)d_in[4];
  const float* Wv    = (const float*)d_in[5];
  const float* bv    = (const float*)d_in[6];
  const float* gamma = (const float*)d_in[7];
  float* out = (float*)d_out;

  unsigned short* Qb = (unsigned short*)d_ws;                 // 256 KB
  unsigned short* Kb = Qb + (size_t)NB * NPOS * CQK;          // 256 KB
  unsigned short* VB = Kb + (size_t)NB * NPOS * CQK;          // 2 MB (blocked layout)

  qkv_proj<<<dim3(NB * NPOS / 32), dim3(256), 0, stream>>>(
      x, Wq, bq, Wk, bk, Wv, bv, Qb, Kb, VB);
  flash_attn<<<dim3(NB * NPOS / 64), dim3(512), 0, stream>>>(
      Qb, Kb, VB, x, gamma, out);
}